// Round 8
// baseline (160.165 us; speedup 1.0000x reference)
//
#include <hip/hip_runtime.h>

// LR_PINN_phase2_midout: fused 4-stage tiny MLP, N=262144, H=256, R=32.
// R8: attack the transcendental pipe. R7's neutral result + counters
// (VALUBusy 72% + MfmaUtil 24% ~= 96%) showed the SIMD is issue-saturated;
// calibration gives trans ops ~14.5 cyc/wave-instr -> tanh's exp2+rcp pairs
// are ~57% of the wall. Two changes:
//  (1) 8-way batched reciprocal: 1/(1+e_i) for 8 co-live elements via a
//      product tree + ONE rcp (trans per tanh: 2 -> 1.125). exp2 outputs
//      clamped to 2^15 so the 8-product stays finite (no octet poisoning;
//      clamp error <= 6.1e-5, below fp16 ulp).
//  (2) emit inv (=1/(1+e)) instead of tanh=1-2*inv: fold -2 into ctf & ew,
//      and init GEMM1 accumulators with rowsums sum_j(alpha*Ct[r][j])
//      (computed from the SAME fp16 LDS values -> no new weight error):
//      P = rs + sum((-2 a Ct) * inv) == sum(a Ct * (1-2 inv)). Epilogue dot
//      likewise: ssum starts at per-lane ewsum (g-invariant, hoisted).
//
// Kept from R4-R7: mfma_f32_16x16x16f16 layout-closed chain (C/D row=4q+reg
// == next B-frag k=4q+jj; zero LDS round-trips/barriers in steady state),
// fragment-ordered conflict-free LDS, strict #pragma unroll 1 (the 64-VGPR
// arch budget spills under any wide unroll), dual point-tile streams.

typedef _Float16 half4_t __attribute__((ext_vector_type(4)));
typedef float    float4_t __attribute__((ext_vector_type(4)));

#define TANH_SCALE 2.885390081777927f  // 2*log2(e); exp2(S*x) == exp(2x)
#define ECLAMP 32768.0f                // 2^15: (2^15+1)^8 < 2^128 -> tree stays finite

namespace {

struct alignas(16) Smem {
  // entry index e = ((k*16+t)*2+sel)*64+lane ; one half4 (8 B) per lane.
  half4_t ctf[3 * 16 * 2 * 64];  // 48 KB: -2 * alpha * Ct[sel*16+m][16t+4q+jj]
  half4_t rwf[3 * 16 * 2 * 64];  // 48 KB:  S * R[16t+m][sel*16+4q+jj]
  float w0[256], w1[256], bb[256];  // pre-scaled by S
  float ew[256];                    // -2 * end_w
  float rsC[3 * 32];                // rowsums: sum_j alpha*Ct[r][j]
};

// inv_i = 1/(1+min(exp2(v_i),2^15)) for 8 elements, single rcp.
// tanh(x) = 1 - 2*inv  (the -2 and +1 are folded into weights/rowsums).
__device__ __forceinline__ void inv8(float4_t v0, float4_t v1,
                                     float4_t& i0, float4_t& i1) {
  const float a0 = fminf(__builtin_amdgcn_exp2f(v0.x), ECLAMP) + 1.0f;
  const float a1 = fminf(__builtin_amdgcn_exp2f(v0.y), ECLAMP) + 1.0f;
  const float a2 = fminf(__builtin_amdgcn_exp2f(v0.z), ECLAMP) + 1.0f;
  const float a3 = fminf(__builtin_amdgcn_exp2f(v0.w), ECLAMP) + 1.0f;
  const float a4 = fminf(__builtin_amdgcn_exp2f(v1.x), ECLAMP) + 1.0f;
  const float a5 = fminf(__builtin_amdgcn_exp2f(v1.y), ECLAMP) + 1.0f;
  const float a6 = fminf(__builtin_amdgcn_exp2f(v1.z), ECLAMP) + 1.0f;
  const float a7 = fminf(__builtin_amdgcn_exp2f(v1.w), ECLAMP) + 1.0f;
  const float p01 = a0 * a1, p23 = a2 * a3, p45 = a4 * a5, p67 = a6 * a7;
  const float q03 = p01 * p23, q47 = p45 * p67;
  const float rd = __builtin_amdgcn_rcpf(q03 * q47);
  const float s03 = rd * q47, s47 = rd * q03;   // 1/q03, 1/q47
  const float t01 = s03 * p23, t23 = s03 * p01; // 1/p01, 1/p23
  const float t45 = s47 * p67, t67 = s47 * p45;
  i0.x = t01 * a1; i0.y = t01 * a0; i0.z = t23 * a3; i0.w = t23 * a2;
  i1.x = t45 * a5; i1.y = t45 * a4; i1.z = t67 * a7; i1.w = t67 * a6;
}

__device__ __forceinline__ half4_t pack16(float4_t v) {
  half4_t h;
  h.x = (_Float16)v.x; h.y = (_Float16)v.y; h.z = (_Float16)v.z; h.w = (_Float16)v.w;
  return h;
}

__global__ __launch_bounds__(1024)
__attribute__((amdgpu_waves_per_eu(4, 4)))
void pinn_fused(
    const float* __restrict__ xg, const float* __restrict__ tg,
    const float* __restrict__ sw, const float* __restrict__ sb,
    const float* __restrict__ ewp, const float* __restrict__ ebp,
    const float* __restrict__ c0, const float* __restrict__ c1,
    const float* __restrict__ c2, const float* __restrict__ r0,
    const float* __restrict__ r1, const float* __restrict__ r2,
    const float* __restrict__ a0, const float* __restrict__ a1,
    const float* __restrict__ a2, float* __restrict__ out, int n)
{
  __shared__ Smem sm;
  const int tid = threadIdx.x;

  // ---- stage weights into fragment-ordered fp16 LDS (once per block) ----
  for (int e = tid; e < 3 * 16 * 2 * 64; e += 1024) {
    const int lane_ = e & 63;
    const int sel   = (e >> 6) & 1;
    const int t_    = (e >> 7) & 15;
    const int k_    = e >> 11;
    const int m_ = lane_ & 15, q_ = lane_ >> 4;
    const float* ck = (k_ == 0) ? c0 : (k_ == 1) ? c1 : c2;
    const float* rk = (k_ == 0) ? r0 : (k_ == 1) ? r1 : r2;
    const float* ak = (k_ == 0) ? a0 : (k_ == 1) ? a1 : a2;
    {  // Ct frag: A-row r = sel*16+m, cols j = 16t+4q+jj ; fold -2*alpha
      const int r = sel * 16 + m_;
      const float av = ak[r] * -2.0f;
      const int j0 = 16 * t_ + 4 * q_;
      half4_t v;
      v.x = (_Float16)(ck[(j0 + 0) * 32 + r] * av);
      v.y = (_Float16)(ck[(j0 + 1) * 32 + r] * av);
      v.z = (_Float16)(ck[(j0 + 2) * 32 + r] * av);
      v.w = (_Float16)(ck[(j0 + 3) * 32 + r] * av);
      sm.ctf[e] = v;
    }
    {  // R frag: A-row j = 16t+m, cols r = sel*16+4q+jj ; fold tanh scale S
      const int j = 16 * t_ + m_;
      const int rr = sel * 16 + 4 * q_;
      half4_t v;
      v.x = (_Float16)(rk[j * 32 + rr + 0] * TANH_SCALE);
      v.y = (_Float16)(rk[j * 32 + rr + 1] * TANH_SCALE);
      v.z = (_Float16)(rk[j * 32 + rr + 2] * TANH_SCALE);
      v.w = (_Float16)(rk[j * 32 + rr + 3] * TANH_SCALE);
      sm.rwf[e] = v;
    }
  }
  if (tid < 256) {
    sm.w0[tid] = sw[2 * tid] * TANH_SCALE;      // fold tanh scale S
    sm.w1[tid] = sw[2 * tid + 1] * TANH_SCALE;
    sm.bb[tid] = sb[tid] * TANH_SCALE;
    sm.ew[tid] = ewp[tid] * -2.0f;              // fold -2
  }
  __syncthreads();

  // ---- rowsums rsC[k][r] = sum_j alpha*Ct[r][j] = -0.5 * sum(ctf frags) ----
  if (tid < 96) {
    const int k_ = tid >> 5, r = tid & 31;
    const int sel = r >> 4, mm = r & 15;
    float s = 0.0f;
    for (int t = 0; t < 16; ++t)
      for (int qq = 0; qq < 4; ++qq) {
        const half4_t v = sm.ctf[((k_ * 16 + t) * 2 + sel) * 64 + 16 * qq + mm];
        s += (float)v.x + (float)v.y + (float)v.z + (float)v.w;
      }
    sm.rsC[k_ * 32 + r] = -0.5f * s;
  }
  __syncthreads();

  const int wave = tid >> 6;
  const int lane = tid & 63;
  const int m = lane & 15;   // point index (MFMA col / A-row / B-col)
  const int q = lane >> 4;   // quad
  const int wo = 4 * q;      // j = 16t + 4q + jj
  const float ebv = ebp[0];
  const int tiles = n >> 4;

  // per-lane ewsum = sum over this lane's j-subset of end_w (g-invariant)
  float ewsum = 0.0f;
  for (int t = 0; t < 16; ++t) {
    const float4_t e4 = *(const float4_t*)&sm.ew[t * 16 + wo];  // = -2*ew
    ewsum += e4.x + e4.y + e4.z + e4.w;
  }
  ewsum *= -0.5f;

#pragma unroll 1
  for (int g = blockIdx.x * 32 + wave * 2; g < tiles; g += 8192) {
    const int n0 = g * 16;
    const int n1 = n0 + 16;
    const float xm0 = xg[n0 + m], tm0 = tg[n0 + m];
    const float xm1 = xg[n1 + m], tm1 = tg[n1 + m];

    // ---- phase0 fused with GEMM1(k=0); accs init with rowsums ----
    const float4_t rs00 = *(const float4_t*)&sm.rsC[0 * 32 + wo];
    const float4_t rs01 = *(const float4_t*)&sm.rsC[0 * 32 + 16 + wo];
    float4_t a00 = rs00, a01 = rs01;   // stream 0
    float4_t a10 = rs00, a11 = rs01;   // stream 1
#pragma unroll 1
    for (int t = 0; t < 16; ++t) {
      const int cb = t * 16 + wo;
      const float4_t w0v = *(const float4_t*)&sm.w0[cb];
      const float4_t w1v = *(const float4_t*)&sm.w1[cb];
      const float4_t bv  = *(const float4_t*)&sm.bb[cb];
      float4_t z0, z1;
      z0.x = fmaf(xm0, w0v.x, fmaf(tm0, w1v.x, bv.x));
      z1.x = fmaf(xm1, w0v.x, fmaf(tm1, w1v.x, bv.x));
      z0.y = fmaf(xm0, w0v.y, fmaf(tm0, w1v.y, bv.y));
      z1.y = fmaf(xm1, w0v.y, fmaf(tm1, w1v.y, bv.y));
      z0.z = fmaf(xm0, w0v.z, fmaf(tm0, w1v.z, bv.z));
      z1.z = fmaf(xm1, w0v.z, fmaf(tm1, w1v.z, bv.z));
      z0.w = fmaf(xm0, w0v.w, fmaf(tm0, w1v.w, bv.w));
      z1.w = fmaf(xm1, w0v.w, fmaf(tm1, w1v.w, bv.w));
      float4_t i0, i1;
      inv8(z0, z1, i0, i1);
      const half4_t h0 = pack16(i0);
      const half4_t h1 = pack16(i1);
      const half4_t cA = sm.ctf[t * 128 + lane];
      const half4_t cB = sm.ctf[t * 128 + 64 + lane];
      a00 = __builtin_amdgcn_mfma_f32_16x16x16f16(cA, h0, a00, 0, 0, 0);
      a10 = __builtin_amdgcn_mfma_f32_16x16x16f16(cA, h1, a10, 0, 0, 0);
      a01 = __builtin_amdgcn_mfma_f32_16x16x16f16(cB, h0, a01, 0, 0, 0);
      a11 = __builtin_amdgcn_mfma_f32_16x16x16f16(cB, h1, a11, 0, 0, 0);
    }

    float ssum0 = ewsum, ssum1 = ewsum;
#pragma unroll 1
    for (int k = 0; k < 3; ++k) {
      // acc (= P^T, r = 4q+reg) is already the next B-frag: just pack fp16.
      const half4_t pA0 = pack16(a00), pB0 = pack16(a01);
      const half4_t pA1 = pack16(a10), pB1 = pack16(a11);

      if (k < 2) {
        // GEMM2(k) fused with GEMM1(k+1); accs init with rowsums(k+1).
        const float4_t rsA = *(const float4_t*)&sm.rsC[(k + 1) * 32 + wo];
        const float4_t rsB = *(const float4_t*)&sm.rsC[(k + 1) * 32 + 16 + wo];
        float4_t n00 = rsA, n01 = rsB, n10 = rsA, n11 = rsB;
        const half4_t* rp = &sm.rwf[k * 2048 + lane];
        const half4_t* cp = &sm.ctf[(k + 1) * 2048 + lane];
#pragma unroll 1
        for (int t = 0; t < 16; ++t) {
          const half4_t rA = rp[0], rB = rp[64];
          const half4_t cA = cp[0], cB = cp[64];
          float4_t hc0 = {0.f, 0.f, 0.f, 0.f};
          float4_t hc1 = {0.f, 0.f, 0.f, 0.f};
          hc0 = __builtin_amdgcn_mfma_f32_16x16x16f16(rA, pA0, hc0, 0, 0, 0);
          hc1 = __builtin_amdgcn_mfma_f32_16x16x16f16(rA, pA1, hc1, 0, 0, 0);
          hc0 = __builtin_amdgcn_mfma_f32_16x16x16f16(rB, pB0, hc0, 0, 0, 0);
          hc1 = __builtin_amdgcn_mfma_f32_16x16x16f16(rB, pB1, hc1, 0, 0, 0);
          float4_t i0, i1;
          inv8(hc0, hc1, i0, i1);                  // rwf pre-scaled by S
          const half4_t h0 = pack16(i0);
          const half4_t h1 = pack16(i1);
          n00 = __builtin_amdgcn_mfma_f32_16x16x16f16(cA, h0, n00, 0, 0, 0);
          n10 = __builtin_amdgcn_mfma_f32_16x16x16f16(cA, h1, n10, 0, 0, 0);
          n01 = __builtin_amdgcn_mfma_f32_16x16x16f16(cB, h0, n01, 0, 0, 0);
          n11 = __builtin_amdgcn_mfma_f32_16x16x16f16(cB, h1, n11, 0, 0, 0);
          rp += 128;
          cp += 128;
        }
        a00 = n00; a01 = n01; a10 = n10; a11 = n11;
      } else {
        // last block: GEMM2(2) fused with the end_w dot; ew holds -2*ew,
        // ssum was initialized with +sum(ew): out = sum(ew*tanh) correct.
        const half4_t* rp = &sm.rwf[2 * 2048 + lane];
#pragma unroll 1
        for (int t = 0; t < 16; ++t) {
          const half4_t rA = rp[0], rB = rp[64];
          float4_t hc0 = {0.f, 0.f, 0.f, 0.f};
          float4_t hc1 = {0.f, 0.f, 0.f, 0.f};
          hc0 = __builtin_amdgcn_mfma_f32_16x16x16f16(rA, pA0, hc0, 0, 0, 0);
          hc1 = __builtin_amdgcn_mfma_f32_16x16x16f16(rA, pA1, hc1, 0, 0, 0);
          hc0 = __builtin_amdgcn_mfma_f32_16x16x16f16(rB, pB0, hc0, 0, 0, 0);
          hc1 = __builtin_amdgcn_mfma_f32_16x16x16f16(rB, pB1, hc1, 0, 0, 0);
          float4_t i0, i1;
          inv8(hc0, hc1, i0, i1);
          const float4_t ev = *(const float4_t*)&sm.ew[t * 16 + wo];  // -2*ew
          ssum0 += ev.x * i0.x + ev.y * i0.y + ev.z * i0.z + ev.w * i0.w;
          ssum1 += ev.x * i1.x + ev.y * i1.y + ev.z * i1.z + ev.w * i1.w;
          rp += 128;
        }
      }
    }
    // reduce each stream's partial dot over the 4 quads
    ssum0 += __shfl_xor(ssum0, 16);
    ssum0 += __shfl_xor(ssum0, 32);
    ssum1 += __shfl_xor(ssum1, 16);
    ssum1 += __shfl_xor(ssum1, 32);
    if (lane < 16) {
      out[n0 + m] = ssum0 + ebv;
      out[n1 + m] = ssum1 + ebv;
    }
  }
}

}  // namespace

extern "C" void kernel_launch(void* const* d_in, const int* in_sizes, int n_in,
                              void* d_out, int out_size, void* d_ws, size_t ws_size,
                              hipStream_t stream) {
  const float* xg  = (const float*)d_in[0];
  const float* tg  = (const float*)d_in[1];
  const float* sw  = (const float*)d_in[2];
  const float* sb  = (const float*)d_in[3];
  const float* ewp = (const float*)d_in[4];
  const float* ebp = (const float*)d_in[5];
  const float* c0  = (const float*)d_in[6];
  const float* c1  = (const float*)d_in[7];
  const float* c2  = (const float*)d_in[8];
  const float* r0  = (const float*)d_in[9];
  const float* r1  = (const float*)d_in[10];
  const float* r2  = (const float*)d_in[11];
  const float* a0  = (const float*)d_in[12];
  const float* a1  = (const float*)d_in[13];
  const float* a2  = (const float*)d_in[14];
  float* outp = (float*)d_out;

  const int n = in_sizes[0];  // 262144

  pinn_fused<<<256, 1024, 0, stream>>>(xg, tg, sw, sb, ewp, ebp,
                                       c0, c1, c2, r0, r1, r2, a0, a1, a2,
                                       outp, n);
}

// Round 10
// 150.084 us; speedup vs baseline: 1.0672x; 1.0672x over previous
//
#include <hip/hip_runtime.h>

// LR_PINN_phase2_midout: fused 4-stage tiny MLP, N=262144, H=256, R=32.
// R10 = R9 with the cvt_pkrtz type fix (builtin returns __fp16x2, bit-cast
// to _Float16x2 via union). R9 design recap:
//  (a) explicit v_cvt_pkrtz packing (2 instr per half4 f32->f16)
//  (b) hoisted zero4 as MFMA C-operand for fresh accumulators
//  (c) 1-stage cross-body software pipeline of the COMPUTE chain: in body t,
//      hc_{t+1} (4 MFMAs off loop-invariant pf + fresh frags) issues next to
//      tanh(hc_t) -> the serial MFMA->tanh->MFMA chain is broken across
//      bodies (R8 showed stalls, not trans issue, are the ~28% gap).
// Final body of each t-loop peeled (no out-of-layer frag reads).
//
// Kept: mfma_f32_16x16x16f16 layout-closed chain (C/D row=4q+reg == next
// B-frag k=4q+jj; zero LDS round-trips/barriers in steady state),
// fragment-ordered conflict-free LDS (base+lane*8), strict #pragma unroll 1
// (64-VGPR arch budget spills under any wide unroll), dual point streams,
// tanh scale 2*log2e folded into w0/w1/bb and rwf at staging.

typedef _Float16 half4_t __attribute__((ext_vector_type(4)));
typedef _Float16 half2_t __attribute__((ext_vector_type(2)));
typedef __fp16   fp16x2  __attribute__((ext_vector_type(2)));
typedef float    float4_t __attribute__((ext_vector_type(4)));

#define TANH_SCALE 2.885390081777927f  // 2*log2(e); exp2(S*x) == exp(2x)
#define MFMA16 __builtin_amdgcn_mfma_f32_16x16x16f16

namespace {

struct alignas(16) Smem {
  // entry index e = ((k*16+t)*2+sel)*64+lane ; one half4 (8 B) per lane.
  half4_t ctf[3 * 16 * 2 * 64];  // 48 KB: alpha * Ct[sel*16+m][16t+4q+jj]
  half4_t rwf[3 * 16 * 2 * 64];  // 48 KB: S * R[16t+m][sel*16+4q+jj]
  float w0[256], w1[256], bb[256];  // pre-scaled by S
  float ew[256];
};

__device__ __forceinline__ half4_t pack4(float4_t v) {
  union { fp16x2 f2[2]; half4_t h4; } u;
  u.f2[0] = __builtin_amdgcn_cvt_pkrtz(v.x, v.y);
  u.f2[1] = __builtin_amdgcn_cvt_pkrtz(v.z, v.w);
  return u.h4;
}

// input pre-scaled by S: tanh(x) = 1 - 2/(1 + exp2(S*x)); exact sat at +-inf.
__device__ __forceinline__ float tanh_pre(float y) {
  const float e = __builtin_amdgcn_exp2f(y);
  return fmaf(-2.0f, __builtin_amdgcn_rcpf(e + 1.0f), 1.0f);
}

__device__ __forceinline__ half4_t tanh4(float4_t v) {
  float4_t r;
  r.x = tanh_pre(v.x); r.y = tanh_pre(v.y);
  r.z = tanh_pre(v.z); r.w = tanh_pre(v.w);
  return pack4(r);
}

__global__ __launch_bounds__(1024)
__attribute__((amdgpu_waves_per_eu(4, 4)))
void pinn_fused(
    const float* __restrict__ xg, const float* __restrict__ tg,
    const float* __restrict__ sw, const float* __restrict__ sb,
    const float* __restrict__ ewp, const float* __restrict__ ebp,
    const float* __restrict__ c0, const float* __restrict__ c1,
    const float* __restrict__ c2, const float* __restrict__ r0,
    const float* __restrict__ r1, const float* __restrict__ r2,
    const float* __restrict__ a0, const float* __restrict__ a1,
    const float* __restrict__ a2, float* __restrict__ out, int n)
{
  __shared__ Smem sm;
  const int tid = threadIdx.x;

  // ---- stage weights into fragment-ordered fp16 LDS (once per block) ----
  for (int e = tid; e < 3 * 16 * 2 * 64; e += 1024) {
    const int lane_ = e & 63;
    const int sel   = (e >> 6) & 1;
    const int t_    = (e >> 7) & 15;
    const int k_    = e >> 11;
    const int m_ = lane_ & 15, q_ = lane_ >> 4;
    const float* ck = (k_ == 0) ? c0 : (k_ == 1) ? c1 : c2;
    const float* rk = (k_ == 0) ? r0 : (k_ == 1) ? r1 : r2;
    const float* ak = (k_ == 0) ? a0 : (k_ == 1) ? a1 : a2;
    {  // Ct frag: A-row r = sel*16+m, cols j = 16t+4q+jj ; fold diag(alpha)
      const int r = sel * 16 + m_;
      const float av = ak[r];
      const int j0 = 16 * t_ + 4 * q_;
      half4_t v;
      v.x = (_Float16)(ck[(j0 + 0) * 32 + r] * av);
      v.y = (_Float16)(ck[(j0 + 1) * 32 + r] * av);
      v.z = (_Float16)(ck[(j0 + 2) * 32 + r] * av);
      v.w = (_Float16)(ck[(j0 + 3) * 32 + r] * av);
      sm.ctf[e] = v;
    }
    {  // R frag: A-row j = 16t+m, cols r = sel*16+4q+jj ; fold tanh scale S
      const int j = 16 * t_ + m_;
      const int rr = sel * 16 + 4 * q_;
      half4_t v;
      v.x = (_Float16)(rk[j * 32 + rr + 0] * TANH_SCALE);
      v.y = (_Float16)(rk[j * 32 + rr + 1] * TANH_SCALE);
      v.z = (_Float16)(rk[j * 32 + rr + 2] * TANH_SCALE);
      v.w = (_Float16)(rk[j * 32 + rr + 3] * TANH_SCALE);
      sm.rwf[e] = v;
    }
  }
  if (tid < 256) {
    sm.w0[tid] = sw[2 * tid] * TANH_SCALE;
    sm.w1[tid] = sw[2 * tid + 1] * TANH_SCALE;
    sm.bb[tid] = sb[tid] * TANH_SCALE;
    sm.ew[tid] = ewp[tid];
  }
  __syncthreads();  // the only barrier

  const int wave = tid >> 6;
  const int lane = tid & 63;
  const int m = lane & 15;   // point index (MFMA col / A-row / B-col)
  const int q = lane >> 4;   // quad
  const int wo = 4 * q;      // j = 16t + 4q + jj
  const float ebv = ebp[0];
  const int tiles = n >> 4;

  const float4_t z4 = {0.f, 0.f, 0.f, 0.f};  // hoisted MFMA C-operand zero

#pragma unroll 1
  for (int g = blockIdx.x * 32 + wave * 2; g < tiles; g += 8192) {
    const int n0 = g * 16;
    const int n1 = n0 + 16;
    const float xm0 = xg[n0 + m], tm0 = tg[n0 + m];
    const float xm1 = xg[n1 + m], tm1 = tg[n1 + m];

    // ---- phase0 fused with GEMM1(k=0); z pipelined one body ahead ----
    float4_t a00 = z4, a01 = z4, a10 = z4, a11 = z4;
    float4_t zc0, zc1;
    {
      const float4_t w0v = *(const float4_t*)&sm.w0[wo];
      const float4_t w1v = *(const float4_t*)&sm.w1[wo];
      const float4_t bv  = *(const float4_t*)&sm.bb[wo];
      zc0.x = fmaf(xm0, w0v.x, fmaf(tm0, w1v.x, bv.x));
      zc1.x = fmaf(xm1, w0v.x, fmaf(tm1, w1v.x, bv.x));
      zc0.y = fmaf(xm0, w0v.y, fmaf(tm0, w1v.y, bv.y));
      zc1.y = fmaf(xm1, w0v.y, fmaf(tm1, w1v.y, bv.y));
      zc0.z = fmaf(xm0, w0v.z, fmaf(tm0, w1v.z, bv.z));
      zc1.z = fmaf(xm1, w0v.z, fmaf(tm1, w1v.z, bv.z));
      zc0.w = fmaf(xm0, w0v.w, fmaf(tm0, w1v.w, bv.w));
      zc1.w = fmaf(xm1, w0v.w, fmaf(tm1, w1v.w, bv.w));
    }
    const half4_t* cp0 = &sm.ctf[lane];
#pragma unroll 1
    for (int t = 0; t < 15; ++t) {
      const int cb = (t + 1) * 16 + wo;
      const float4_t w0v = *(const float4_t*)&sm.w0[cb];
      const float4_t w1v = *(const float4_t*)&sm.w1[cb];
      const float4_t bv  = *(const float4_t*)&sm.bb[cb];
      const half4_t h0 = tanh4(zc0);
      const half4_t h1 = tanh4(zc1);
      float4_t zn0, zn1;
      zn0.x = fmaf(xm0, w0v.x, fmaf(tm0, w1v.x, bv.x));
      zn1.x = fmaf(xm1, w0v.x, fmaf(tm1, w1v.x, bv.x));
      zn0.y = fmaf(xm0, w0v.y, fmaf(tm0, w1v.y, bv.y));
      zn1.y = fmaf(xm1, w0v.y, fmaf(tm1, w1v.y, bv.y));
      zn0.z = fmaf(xm0, w0v.z, fmaf(tm0, w1v.z, bv.z));
      zn1.z = fmaf(xm1, w0v.z, fmaf(tm1, w1v.z, bv.z));
      zn0.w = fmaf(xm0, w0v.w, fmaf(tm0, w1v.w, bv.w));
      zn1.w = fmaf(xm1, w0v.w, fmaf(tm1, w1v.w, bv.w));
      const half4_t cA = cp0[0], cB = cp0[64];
      a00 = MFMA16(cA, h0, a00, 0, 0, 0);
      a10 = MFMA16(cA, h1, a10, 0, 0, 0);
      a01 = MFMA16(cB, h0, a01, 0, 0, 0);
      a11 = MFMA16(cB, h1, a11, 0, 0, 0);
      zc0 = zn0; zc1 = zn1;
      cp0 += 128;
    }
    {  // peeled t=15
      const half4_t h0 = tanh4(zc0);
      const half4_t h1 = tanh4(zc1);
      const half4_t cA = cp0[0], cB = cp0[64];
      a00 = MFMA16(cA, h0, a00, 0, 0, 0);
      a10 = MFMA16(cA, h1, a10, 0, 0, 0);
      a01 = MFMA16(cB, h0, a01, 0, 0, 0);
      a11 = MFMA16(cB, h1, a11, 0, 0, 0);
    }

#pragma unroll 1
    for (int k = 0; k < 2; ++k) {
      // acc (= P^T, r = 4q+reg) is already the next B-frag (loop-invariant).
      const half4_t pA0 = pack4(a00), pB0 = pack4(a01);
      const half4_t pA1 = pack4(a10), pB1 = pack4(a11);
      const half4_t* rp = &sm.rwf[k * 2048 + lane];
      const half4_t* cp = &sm.ctf[(k + 1) * 2048 + lane];
      float4_t hc0, hc1;
      {  // prologue: hc for t=0
        const half4_t rA = rp[0], rB = rp[64];
        hc0 = MFMA16(rA, pA0, z4, 0, 0, 0);
        hc1 = MFMA16(rA, pA1, z4, 0, 0, 0);
        hc0 = MFMA16(rB, pB0, hc0, 0, 0, 0);
        hc1 = MFMA16(rB, pB1, hc1, 0, 0, 0);
      }
      float4_t n00 = z4, n01 = z4, n10 = z4, n11 = z4;
#pragma unroll 1
      for (int t = 0; t < 15; ++t) {
        const half4_t rA = rp[128], rB = rp[192];  // frags for t+1
        const half4_t cA = cp[0],  cB = cp[64];
        const half4_t h0 = tanh4(hc0);             // hc from body t-1
        const half4_t h1 = tanh4(hc1);
        float4_t u0 = MFMA16(rA, pA0, z4, 0, 0, 0);  // hc_{t+1}: independent
        float4_t u1 = MFMA16(rA, pA1, z4, 0, 0, 0);
        u0 = MFMA16(rB, pB0, u0, 0, 0, 0);
        u1 = MFMA16(rB, pB1, u1, 0, 0, 0);
        n00 = MFMA16(cA, h0, n00, 0, 0, 0);
        n10 = MFMA16(cA, h1, n10, 0, 0, 0);
        n01 = MFMA16(cB, h0, n01, 0, 0, 0);
        n11 = MFMA16(cB, h1, n11, 0, 0, 0);
        hc0 = u0; hc1 = u1;
        rp += 128; cp += 128;
      }
      {  // peeled t=15
        const half4_t cA = cp[0], cB = cp[64];
        const half4_t h0 = tanh4(hc0);
        const half4_t h1 = tanh4(hc1);
        n00 = MFMA16(cA, h0, n00, 0, 0, 0);
        n10 = MFMA16(cA, h1, n10, 0, 0, 0);
        n01 = MFMA16(cB, h0, n01, 0, 0, 0);
        n11 = MFMA16(cB, h1, n11, 0, 0, 0);
      }
      a00 = n00; a01 = n01; a10 = n10; a11 = n11;
    }

    // ---- k=2: GEMM2(2) fused with the end_w dot (fp32), hc pipelined ----
    float ssum0 = 0.0f, ssum1 = 0.0f;
    {
      const half4_t pA0 = pack4(a00), pB0 = pack4(a01);
      const half4_t pA1 = pack4(a10), pB1 = pack4(a11);
      const half4_t* rp = &sm.rwf[2 * 2048 + lane];
      float4_t hc0, hc1;
      {
        const half4_t rA = rp[0], rB = rp[64];
        hc0 = MFMA16(rA, pA0, z4, 0, 0, 0);
        hc1 = MFMA16(rA, pA1, z4, 0, 0, 0);
        hc0 = MFMA16(rB, pB0, hc0, 0, 0, 0);
        hc1 = MFMA16(rB, pB1, hc1, 0, 0, 0);
      }
#pragma unroll 1
      for (int t = 0; t < 15; ++t) {
        const half4_t rA = rp[128], rB = rp[192];
        const float4_t ev = *(const float4_t*)&sm.ew[t * 16 + wo];
        float4_t u0 = MFMA16(rA, pA0, z4, 0, 0, 0);
        float4_t u1 = MFMA16(rA, pA1, z4, 0, 0, 0);
        u0 = MFMA16(rB, pB0, u0, 0, 0, 0);
        u1 = MFMA16(rB, pB1, u1, 0, 0, 0);
        ssum0 = fmaf(ev.x, tanh_pre(hc0.x), ssum0);
        ssum1 = fmaf(ev.x, tanh_pre(hc1.x), ssum1);
        ssum0 = fmaf(ev.y, tanh_pre(hc0.y), ssum0);
        ssum1 = fmaf(ev.y, tanh_pre(hc1.y), ssum1);
        ssum0 = fmaf(ev.z, tanh_pre(hc0.z), ssum0);
        ssum1 = fmaf(ev.z, tanh_pre(hc1.z), ssum1);
        ssum0 = fmaf(ev.w, tanh_pre(hc0.w), ssum0);
        ssum1 = fmaf(ev.w, tanh_pre(hc1.w), ssum1);
        hc0 = u0; hc1 = u1;
        rp += 128;
      }
      {  // peeled t=15
        const float4_t ev = *(const float4_t*)&sm.ew[240 + wo];
        ssum0 = fmaf(ev.x, tanh_pre(hc0.x), ssum0);
        ssum1 = fmaf(ev.x, tanh_pre(hc1.x), ssum1);
        ssum0 = fmaf(ev.y, tanh_pre(hc0.y), ssum0);
        ssum1 = fmaf(ev.y, tanh_pre(hc1.y), ssum1);
        ssum0 = fmaf(ev.z, tanh_pre(hc0.z), ssum0);
        ssum1 = fmaf(ev.z, tanh_pre(hc1.z), ssum1);
        ssum0 = fmaf(ev.w, tanh_pre(hc0.w), ssum0);
        ssum1 = fmaf(ev.w, tanh_pre(hc1.w), ssum1);
      }
    }

    // reduce each stream's partial dot over the 4 quads
    ssum0 += __shfl_xor(ssum0, 16);
    ssum0 += __shfl_xor(ssum0, 32);
    ssum1 += __shfl_xor(ssum1, 16);
    ssum1 += __shfl_xor(ssum1, 32);
    if (lane < 16) {
      out[n0 + m] = ssum0 + ebv;
      out[n1 + m] = ssum1 + ebv;
    }
  }
}

}  // namespace

extern "C" void kernel_launch(void* const* d_in, const int* in_sizes, int n_in,
                              void* d_out, int out_size, void* d_ws, size_t ws_size,
                              hipStream_t stream) {
  const float* xg  = (const float*)d_in[0];
  const float* tg  = (const float*)d_in[1];
  const float* sw  = (const float*)d_in[2];
  const float* sb  = (const float*)d_in[3];
  const float* ewp = (const float*)d_in[4];
  const float* ebp = (const float*)d_in[5];
  const float* c0  = (const float*)d_in[6];
  const float* c1  = (const float*)d_in[7];
  const float* c2  = (const float*)d_in[8];
  const float* r0  = (const float*)d_in[9];
  const float* r1  = (const float*)d_in[10];
  const float* r2  = (const float*)d_in[11];
  const float* a0  = (const float*)d_in[12];
  const float* a1  = (const float*)d_in[13];
  const float* a2  = (const float*)d_in[14];
  float* outp = (float*)d_out;

  const int n = in_sizes[0];  // 262144

  pinn_fused<<<256, 1024, 0, stream>>>(xg, tg, sw, sb, ewp, ebp,
                                       c0, c1, c2, r0, r1, r2, a0, a1, a2,
                                       outp, n);
}

// Round 11
// 142.952 us; speedup vs baseline: 1.1204x; 1.0499x over previous
//
#include <hip/hip_runtime.h>

// LR_PINN_phase2_midout: fused 4-stage tiny MLP, N=262144, H=256, R=32.
// R11 = R10 with QUAD point-tile streams per wave (4 tiles = 64 points).
// R10 post-mortem: VALUBusy 73% / stall ~27%, VGPR only 52 of a 128 budget
// -> spare registers buy ILP. Per body: 4 independent MFMA->tanh->MFMA
// chains, emitted phase-grouped (all first MFMAs, all second MFMAs, all
// tanhs, all acc MFMAs) so in-order issue never waits on a same-stream
// producer. LDS fragment reads amortized 4x. Cross-body pipelining dropped
// (in-body ILP replaces it, minus the 8 movs/body). Live set ~90 VGPRs.
//
// Kept: mfma_f32_16x16x16f16 layout-closed chain (C/D row=4q+reg == next
// B-frag k=4q+jj; zero LDS round-trips/barriers in steady state),
// fragment-ordered conflict-free LDS (base+lane*8), strict #pragma unroll 1
// on t-loops, v_cvt_pkrtz packing, hoisted zero4 C-operand, tanh scale
// 2*log2e folded into w0/w1/bb and rwf at staging.

typedef _Float16 half4_t __attribute__((ext_vector_type(4)));
typedef __fp16   fp16x2  __attribute__((ext_vector_type(2)));
typedef float    float4_t __attribute__((ext_vector_type(4)));

#define TANH_SCALE 2.885390081777927f  // 2*log2(e); exp2(S*x) == exp(2x)
#define MFMA16 __builtin_amdgcn_mfma_f32_16x16x16f16

namespace {

struct alignas(16) Smem {
  // entry index e = ((k*16+t)*2+sel)*64+lane ; one half4 (8 B) per lane.
  half4_t ctf[3 * 16 * 2 * 64];  // 48 KB: alpha * Ct[sel*16+m][16t+4q+jj]
  half4_t rwf[3 * 16 * 2 * 64];  // 48 KB: S * R[16t+m][sel*16+4q+jj]
  float w0[256], w1[256], bb[256];  // pre-scaled by S
  float ew[256];
};

__device__ __forceinline__ half4_t pack4(float4_t v) {
  union { fp16x2 f2[2]; half4_t h4; } u;
  u.f2[0] = __builtin_amdgcn_cvt_pkrtz(v.x, v.y);
  u.f2[1] = __builtin_amdgcn_cvt_pkrtz(v.z, v.w);
  return u.h4;
}

// input pre-scaled by S: tanh(x) = 1 - 2/(1 + exp2(S*x)); exact sat at +-inf.
__device__ __forceinline__ float tanh_pre(float y) {
  const float e = __builtin_amdgcn_exp2f(y);
  return fmaf(-2.0f, __builtin_amdgcn_rcpf(e + 1.0f), 1.0f);
}

__device__ __forceinline__ half4_t tanh4(float4_t v) {
  float4_t r;
  r.x = tanh_pre(v.x); r.y = tanh_pre(v.y);
  r.z = tanh_pre(v.z); r.w = tanh_pre(v.w);
  return pack4(r);
}

__global__ __launch_bounds__(1024)
__attribute__((amdgpu_waves_per_eu(4, 4)))
void pinn_fused(
    const float* __restrict__ xg, const float* __restrict__ tg,
    const float* __restrict__ sw, const float* __restrict__ sb,
    const float* __restrict__ ewp, const float* __restrict__ ebp,
    const float* __restrict__ c0, const float* __restrict__ c1,
    const float* __restrict__ c2, const float* __restrict__ r0,
    const float* __restrict__ r1, const float* __restrict__ r2,
    const float* __restrict__ a0, const float* __restrict__ a1,
    const float* __restrict__ a2, float* __restrict__ out, int n)
{
  __shared__ Smem sm;
  const int tid = threadIdx.x;

  // ---- stage weights into fragment-ordered fp16 LDS (once per block) ----
  for (int e = tid; e < 3 * 16 * 2 * 64; e += 1024) {
    const int lane_ = e & 63;
    const int sel   = (e >> 6) & 1;
    const int t_    = (e >> 7) & 15;
    const int k_    = e >> 11;
    const int m_ = lane_ & 15, q_ = lane_ >> 4;
    const float* ck = (k_ == 0) ? c0 : (k_ == 1) ? c1 : c2;
    const float* rk = (k_ == 0) ? r0 : (k_ == 1) ? r1 : r2;
    const float* ak = (k_ == 0) ? a0 : (k_ == 1) ? a1 : a2;
    {  // Ct frag: A-row r = sel*16+m, cols j = 16t+4q+jj ; fold diag(alpha)
      const int r = sel * 16 + m_;
      const float av = ak[r];
      const int j0 = 16 * t_ + 4 * q_;
      half4_t v;
      v.x = (_Float16)(ck[(j0 + 0) * 32 + r] * av);
      v.y = (_Float16)(ck[(j0 + 1) * 32 + r] * av);
      v.z = (_Float16)(ck[(j0 + 2) * 32 + r] * av);
      v.w = (_Float16)(ck[(j0 + 3) * 32 + r] * av);
      sm.ctf[e] = v;
    }
    {  // R frag: A-row j = 16t+m, cols r = sel*16+4q+jj ; fold tanh scale S
      const int j = 16 * t_ + m_;
      const int rr = sel * 16 + 4 * q_;
      half4_t v;
      v.x = (_Float16)(rk[j * 32 + rr + 0] * TANH_SCALE);
      v.y = (_Float16)(rk[j * 32 + rr + 1] * TANH_SCALE);
      v.z = (_Float16)(rk[j * 32 + rr + 2] * TANH_SCALE);
      v.w = (_Float16)(rk[j * 32 + rr + 3] * TANH_SCALE);
      sm.rwf[e] = v;
    }
  }
  if (tid < 256) {
    sm.w0[tid] = sw[2 * tid] * TANH_SCALE;
    sm.w1[tid] = sw[2 * tid + 1] * TANH_SCALE;
    sm.bb[tid] = sb[tid] * TANH_SCALE;
    sm.ew[tid] = ewp[tid];
  }
  __syncthreads();  // the only barrier

  const int wave = tid >> 6;
  const int lane = tid & 63;
  const int m = lane & 15;   // point index (MFMA col / A-row / B-col)
  const int q = lane >> 4;   // quad
  const int wo = 4 * q;      // j = 16t + 4q + jj
  const float ebv = ebp[0];
  const int tiles = n >> 4;

  const float4_t z4 = {0.f, 0.f, 0.f, 0.f};  // hoisted MFMA C-operand zero

#pragma unroll 1
  for (int g = (blockIdx.x * 16 + wave) * 4; g < tiles; g += 16384) {
    float xm[4], tm[4];
#pragma unroll
    for (int s = 0; s < 4; ++s) {
      xm[s] = xg[(g + s) * 16 + m];
      tm[s] = tg[(g + s) * 16 + m];
    }

    // ---- phase0 fused with GEMM1(k=0); 4 independent streams per body ----
    float4_t acc[4][2];
#pragma unroll
    for (int s = 0; s < 4; ++s) { acc[s][0] = z4; acc[s][1] = z4; }
    const half4_t* cp0 = &sm.ctf[lane];
#pragma unroll 1
    for (int t = 0; t < 16; ++t) {
      const int cb = t * 16 + wo;
      const float4_t w0v = *(const float4_t*)&sm.w0[cb];
      const float4_t w1v = *(const float4_t*)&sm.w1[cb];
      const float4_t bv  = *(const float4_t*)&sm.bb[cb];
      half4_t h[4];
#pragma unroll
      for (int s = 0; s < 4; ++s) {
        float4_t z;
        z.x = fmaf(xm[s], w0v.x, fmaf(tm[s], w1v.x, bv.x));
        z.y = fmaf(xm[s], w0v.y, fmaf(tm[s], w1v.y, bv.y));
        z.z = fmaf(xm[s], w0v.z, fmaf(tm[s], w1v.z, bv.z));
        z.w = fmaf(xm[s], w0v.w, fmaf(tm[s], w1v.w, bv.w));
        h[s] = tanh4(z);
      }
      const half4_t cA = cp0[0], cB = cp0[64];
#pragma unroll
      for (int s = 0; s < 4; ++s) acc[s][0] = MFMA16(cA, h[s], acc[s][0], 0, 0, 0);
#pragma unroll
      for (int s = 0; s < 4; ++s) acc[s][1] = MFMA16(cB, h[s], acc[s][1], 0, 0, 0);
      cp0 += 128;
    }

#pragma unroll 1
    for (int k = 0; k < 2; ++k) {
      // acc (= P^T, r = 4q+reg) is already the next B-frag: pack, acc dies.
      half4_t pf[4][2];
#pragma unroll
      for (int s = 0; s < 4; ++s) {
        pf[s][0] = pack4(acc[s][0]);
        pf[s][1] = pack4(acc[s][1]);
      }
      float4_t nn[4][2];
#pragma unroll
      for (int s = 0; s < 4; ++s) { nn[s][0] = z4; nn[s][1] = z4; }
      const half4_t* rp = &sm.rwf[k * 2048 + lane];
      const half4_t* cp = &sm.ctf[(k + 1) * 2048 + lane];
#pragma unroll 1
      for (int t = 0; t < 16; ++t) {
        const half4_t rA = rp[0], rB = rp[64];
        const half4_t cA = cp[0], cB = cp[64];
        float4_t u[4];
#pragma unroll
        for (int s = 0; s < 4; ++s) u[s] = MFMA16(rA, pf[s][0], z4, 0, 0, 0);
#pragma unroll
        for (int s = 0; s < 4; ++s) u[s] = MFMA16(rB, pf[s][1], u[s], 0, 0, 0);
        half4_t h[4];
#pragma unroll
        for (int s = 0; s < 4; ++s) h[s] = tanh4(u[s]);
#pragma unroll
        for (int s = 0; s < 4; ++s) nn[s][0] = MFMA16(cA, h[s], nn[s][0], 0, 0, 0);
#pragma unroll
        for (int s = 0; s < 4; ++s) nn[s][1] = MFMA16(cB, h[s], nn[s][1], 0, 0, 0);
        rp += 128; cp += 128;
      }
#pragma unroll
      for (int s = 0; s < 4; ++s) { acc[s][0] = nn[s][0]; acc[s][1] = nn[s][1]; }
    }

    // ---- k=2: GEMM2(2) fused with the end_w dot (fp32 epilogue) ----
    float ssum[4] = {0.f, 0.f, 0.f, 0.f};
    {
      half4_t pf[4][2];
#pragma unroll
      for (int s = 0; s < 4; ++s) {
        pf[s][0] = pack4(acc[s][0]);
        pf[s][1] = pack4(acc[s][1]);
      }
      const half4_t* rp = &sm.rwf[2 * 2048 + lane];
#pragma unroll 1
      for (int t = 0; t < 16; ++t) {
        const half4_t rA = rp[0], rB = rp[64];
        const float4_t ev = *(const float4_t*)&sm.ew[t * 16 + wo];
        float4_t u[4];
#pragma unroll
        for (int s = 0; s < 4; ++s) u[s] = MFMA16(rA, pf[s][0], z4, 0, 0, 0);
#pragma unroll
        for (int s = 0; s < 4; ++s) u[s] = MFMA16(rB, pf[s][1], u[s], 0, 0, 0);
#pragma unroll
        for (int s = 0; s < 4; ++s) {
          ssum[s] = fmaf(ev.x, tanh_pre(u[s].x), ssum[s]);
          ssum[s] = fmaf(ev.y, tanh_pre(u[s].y), ssum[s]);
          ssum[s] = fmaf(ev.z, tanh_pre(u[s].z), ssum[s]);
          ssum[s] = fmaf(ev.w, tanh_pre(u[s].w), ssum[s]);
        }
        rp += 128;
      }
    }

    // reduce each stream's partial dot over the 4 quads
#pragma unroll
    for (int s = 0; s < 4; ++s) {
      ssum[s] += __shfl_xor(ssum[s], 16);
      ssum[s] += __shfl_xor(ssum[s], 32);
    }
    if (lane < 16) {
#pragma unroll
      for (int s = 0; s < 4; ++s) out[(g + s) * 16 + m] = ssum[s] + ebv;
    }
  }
}

}  // namespace

extern "C" void kernel_launch(void* const* d_in, const int* in_sizes, int n_in,
                              void* d_out, int out_size, void* d_ws, size_t ws_size,
                              hipStream_t stream) {
  const float* xg  = (const float*)d_in[0];
  const float* tg  = (const float*)d_in[1];
  const float* sw  = (const float*)d_in[2];
  const float* sb  = (const float*)d_in[3];
  const float* ewp = (const float*)d_in[4];
  const float* ebp = (const float*)d_in[5];
  const float* c0  = (const float*)d_in[6];
  const float* c1  = (const float*)d_in[7];
  const float* c2  = (const float*)d_in[8];
  const float* r0  = (const float*)d_in[9];
  const float* r1  = (const float*)d_in[10];
  const float* r2  = (const float*)d_in[11];
  const float* a0  = (const float*)d_in[12];
  const float* a1  = (const float*)d_in[13];
  const float* a2  = (const float*)d_in[14];
  float* outp = (float*)d_out;

  const int n = in_sizes[0];  // 262144

  pinn_fused<<<256, 1024, 0, stream>>>(xg, tg, sw, sb, ewp, ebp,
                                       c0, c1, c2, r0, r1, r2, a0, a1, a2,
                                       outp, n);
}